// Round 4
// baseline (146.401 us; speedup 1.0000x reference)
//
#include <hip/hip_runtime.h>

typedef unsigned long long u64;
typedef unsigned short u16;
typedef unsigned char u8;

#define VOX 0.4f
#define GAM 1.1f
#define NCX 16        // 16x16 cells
#define CELLW 32.0f   // voxels per cell (power of 2: floor(pvx/32) exact)
#define CAP 64        // max candidate boxes per cell (sentinel fallback if exceeded)

// IEEE f32, no contraction: replicate numpy/jax op-for-op.
__device__ __forceinline__ float dist2d(float ax, float ay, float bx, float by) {
  float dx = __fsub_rn(ax, bx);
  float dy = __fsub_rn(ay, by);
  return __fsqrt_rn(__fadd_rn(__fmul_rn(dx, dx), __fmul_rn(dy, dy)));
}

// metric radius = norm(dims*0.5) * GAMMA
__device__ __forceinline__ float box_radius(const float* __restrict__ boxes, int m) {
  float hx = __fmul_rn(boxes[m * 7 + 3], 0.5f);
  float hy = __fmul_rn(boxes[m * 7 + 4], 0.5f);
  float nr = __fsqrt_rn(__fadd_rn(__fmul_rn(hx, hx), __fmul_rn(hy, hy)));
  return __fmul_rn(nr, GAM);
}

// ---- prep (1 block): voxel-space box arrays + conservative cell->box lists ----
__global__ void k_prep(const float* __restrict__ boxes, const float* __restrict__ pc_start,
                       float* __restrict__ qxv, float* __restrict__ qyv, float* __restrict__ rv,
                       int* __restrict__ cellCnt, u16* __restrict__ cellList, int M) {
  const int t = threadIdx.x;
  const float psx = pc_start[0], psy = pc_start[1];
  for (int m = t; m < M; m += 256) {
    qxv[m] = __fdiv_rn(__fsub_rn(boxes[m * 7 + 0], psx), VOX);
    qyv[m] = __fdiv_rn(__fsub_rn(boxes[m * 7 + 1], psy), VOX);
    float hx = __fmul_rn(boxes[m * 7 + 3], 0.5f);
    float hy = __fmul_rn(boxes[m * 7 + 4], 0.5f);
    float nr = __fsqrt_rn(__fadd_rn(__fmul_rn(hx, hx), __fmul_rn(hy, hy)));
    rv[m] = __fdiv_rn(__fmul_rn(nr, GAM), VOX);
  }
  __syncthreads();  // single block: global writes visible after barrier
  if (t < NCX * NCX) {
    const int cx = t & (NCX - 1), cy = t >> 4;
    const float x0 = (cx == 0) ? -3e38f : cx * CELLW;
    const float x1 = (cx == NCX - 1) ? 3e38f : (cx + 1) * CELLW;
    const float y0 = (cy == 0) ? -3e38f : cy * CELLW;
    const float y1 = (cy == NCX - 1) ? 3e38f : (cy + 1) * CELLW;
    int cnt = 0;
    for (int m = 0; m < M; ++m) {
      const float qx = qxv[m], qy = qyv[m];
      float ddx = fmaxf(0.0f, fmaxf(x0 - qx, qx - x1));
      float ddy = fmaxf(0.0f, fmaxf(y0 - qy, qy - y1));
      float rr = rv[m] + 0.01f;  // conservative margin >> f32 rounding of exact test
      if (ddx * ddx + ddy * ddy <= rr * rr) {
        if (cnt < CAP) cellList[t * CAP + cnt] = (u16)m;
        ++cnt;
      }
    }
    cellCnt[t] = cnt;  // cnt > CAP acts as sentinel -> full fallback loop
  }
}

// ---- fused: binned vmask (strict <) + ORDERED compaction + per-(chunk,box) counts
//      chunk == one block == 256 points. cnt layout: box-major [m][c].
__global__ void k_vmask_count(const float* __restrict__ pts, const float* __restrict__ boxes,
                              const float* __restrict__ qxv, const float* __restrict__ qyv,
                              const float* __restrict__ rv,
                              const int* __restrict__ cellCnt, const u16* __restrict__ cellList,
                              u64* __restrict__ vbits, u8* __restrict__ present,
                              int* __restrict__ cnt,
                              float* __restrict__ cpxg, float* __restrict__ cpyg,
                              int* __restrict__ cpng, int* __restrict__ nflags,
                              const float* __restrict__ pc_start,
                              int N, int M, int nchunk) {
  __shared__ float cpx[256], cpy[256];  // compacted flagged points (metric xy)
  __shared__ int cpn[256];              // compacted point indices
  __shared__ int wcnt[4];
  const int tid = threadIdx.x;
  const int blk = blockIdx.x;
  const int n = blk * 256 + tid;
  const int wv = tid >> 6, lane = tid & 63;
  const float psx = pc_start[0], psy = pc_start[1];
  const bool valid = (n < N);
  float px = 1e6f, py = 1e6f, pvx = 0.f, pvy = 0.f;
  if (valid) {
    px = pts[n * 5 + 0];
    py = pts[n * 5 + 1];
    pvx = __fdiv_rn(__fsub_rn(px, psx), VOX);
    pvy = __fdiv_rn(__fsub_rn(py, psy), VOX);
    present[n] = 0;
  }

  // pass 1: vmask via candidate cells; identical IEEE ops as full loop
  bool flag = false;
  if (valid) {
    int cx = (int)floorf(pvx * (1.0f / CELLW));  // exact: /32 power of two
    int cy = (int)floorf(pvy * (1.0f / CELLW));
    cx = cx < 0 ? 0 : (cx > NCX - 1 ? NCX - 1 : cx);
    cy = cy < 0 ? 0 : (cy > NCX - 1 ? NCX - 1 : cy);
    const int cell = cy * NCX + cx;
    const int k = cellCnt[cell];
    if (k <= CAP) {
      for (int j = 0; j < k; ++j) {
        const int m = cellList[cell * CAP + j];
        float d = dist2d(qxv[m], qyv[m], pvx, pvy);
        if (d < rv[m]) { flag = true; break; }  // strict <
      }
    } else {  // sentinel fallback (dormant for this data)
      for (int m = 0; m < M; ++m) {
        float d = dist2d(qxv[m], qyv[m], pvx, pvy);
        if (d < rv[m]) { flag = true; break; }
      }
    }
  }
  u64 b = __ballot(flag);
  if (lane == 0) {
    vbits[n >> 6] = b;
    wcnt[wv] = __popcll(b);
  }
  __syncthreads();

  // ORDERED compaction (ascending n) of flagged points into LDS, then global
  int base = 0;
  for (int w = 0; w < wv; ++w) base += wcnt[w];
  if (flag) {
    int slot = base + __popcll(b & ((1ULL << lane) - 1ULL));
    cpx[slot] = px;
    cpy[slot] = py;
    cpn[slot] = n;
  }
  __syncthreads();
  const int nfl = wcnt[0] + wcnt[1] + wcnt[2] + wcnt[3];
  if (tid == 0) nflags[blk] = nfl;
  if (tid < nfl) {
    cpxg[blk * 256 + tid] = cpx[tid];
    cpyg[blk * 256 + tid] = cpy[tid];
    cpng[blk * 256 + tid] = cpn[tid];
  }

  // pass 2: thread t owns box t (tiled): count metric matches in this chunk
  for (int t0 = 0; t0 < M; t0 += 256) {
    const int bm = t0 + tid;
    if (bm < M) {
      const float bx = boxes[bm * 7 + 0], by = boxes[bm * 7 + 1];
      const float r = box_radius(boxes, bm);
      int c = 0;
      for (int j = 0; j < nfl; ++j) {
        float d = dist2d(bx, by, cpx[j], cpy[j]);
        c += (d <= r) ? 1 : 0;  // metric space, <=
      }
      cnt[bm * nchunk + blk] = c;  // box-major (coalesced reads in scanbox)
    }
  }
}

// ---- per-box exclusive scan over chunk counts (coalesced reads) ----
__global__ void __launch_bounds__(1024) k_scanbox(const int* __restrict__ cnt,
                                                  int* __restrict__ off,
                                                  int* __restrict__ kcount,
                                                  int nchunk, int M, int S) {
  __shared__ int s[1024];
  const int m = blockIdx.x, t = threadIdx.x;
  int v = (t < nchunk) ? cnt[m * nchunk + t] : 0;
  s[t] = v;
  __syncthreads();
  for (int d = 1; d < 1024; d <<= 1) {
    int x = (t >= d) ? s[t - d] : 0;
    __syncthreads();
    s[t] += x;
    __syncthreads();
  }
  if (t < nchunk) off[t * M + m] = s[t] - v;  // exclusive, chunk-major (for fill)
  if (t == 1023) kcount[m] = (s[t] < S) ? s[t] : S;
}

// ---- merged: fill (blocks [0,nchunk)) + zero-fill (blocks [nchunk,nchunk+M)) ----
__global__ void k_fillz(const float* __restrict__ pts, const float* __restrict__ boxes,
                        const float* __restrict__ cpxg, const float* __restrict__ cpyg,
                        const int* __restrict__ cpng, const int* __restrict__ nflags,
                        const int* __restrict__ off, const u64* __restrict__ vbits,
                        const int* __restrict__ kcount,
                        int* __restrict__ sidx, u8* __restrict__ present,
                        int N, int M, int S, int nchunk) {
  __shared__ float sx[256], sy[256];
  __shared__ int sn[256];
  if ((int)blockIdx.x < nchunk) {
    // ---- fill: chunk-major, thread = box, LDS-staged compacted points ----
    const int c = blockIdx.x;
    const int tid = threadIdx.x;
    const int nf = nflags[c];
    if (nf == 0) return;
    if (tid < nf) {
      sx[tid] = cpxg[c * 256 + tid];
      sy[tid] = cpyg[c * 256 + tid];
      sn[tid] = cpng[c * 256 + tid];
    }
    __syncthreads();
    for (int m = tid; m < M; m += 256) {
      int cum = off[c * M + m];
      if (cum >= S) continue;
      const float bx = boxes[m * 7 + 0], by = boxes[m * 7 + 1];
      const float r = box_radius(boxes, m);
      for (int j = 0; j < nf; ++j) {
        float d = dist2d(bx, by, sx[j], sy[j]);
        if (d <= r) {
          int pn = sn[j];
          sidx[m * S + cum] = pn;
          present[pn] = 1;
          if (++cum >= S) break;
        }
      }
    }
  } else {
    // ---- zero-fill: lowest-index non-matches (top_k tie-break among zeros) ----
    const int m = blockIdx.x - nchunk;
    const int k0 = kcount[m];
    if (k0 >= S) return;
    const int lane = threadIdx.x;
    if (lane >= 64) return;
    const float bx = boxes[m * 7 + 0], by = boxes[m * 7 + 1];
    const float r = box_radius(boxes, m);
    const u64 ltmask = (1ULL << lane) - 1ULL;
    const int nwords = (N + 63) >> 6;
    int fill = k0;
    for (int wi = 0; wi < nwords && fill < S; ++wi) {
      const u64 w = vbits[wi];
      const int n = (wi << 6) + lane;
      bool one = false;
      if (n < N && ((w >> lane) & 1ULL)) {
        float d = dist2d(bx, by, pts[n * 5 + 0], pts[n * 5 + 1]);
        one = (d <= r);
      }
      const bool z = (n < N) && !one;
      u64 b = __ballot(z);
      if (z) {
        int pos = fill + __popcll(b & ltmask);
        if (pos < S) { sidx[m * S + pos] = n; present[n] = 1; }
      }
      fill += __popcll(b);
    }
  }
}

// ------------------------- presence scan (rank = inverse) ----------------------
__global__ void k_bsum(const u8* __restrict__ present, int* __restrict__ bsum, int N) {
  const int n = blockIdx.x * 256 + threadIdx.x;
  bool f = (n < N) && present[n];
  u64 b = __ballot(f);
  __shared__ int ws[4];
  if ((threadIdx.x & 63) == 0) ws[threadIdx.x >> 6] = __popcll(b);
  __syncthreads();
  if (threadIdx.x == 0) bsum[blockIdx.x] = ws[0] + ws[1] + ws[2] + ws[3];
}

__global__ void __launch_bounds__(1024) k_scan(const int* __restrict__ bsum,
                                               int* __restrict__ boff, int nb) {
  __shared__ int s[1024];
  const int t = threadIdx.x;
  int v = (t < nb) ? bsum[t] : 0;
  s[t] = v;
  __syncthreads();
  for (int d = 1; d < 1024; d <<= 1) {
    int x = (t >= d) ? s[t - d] : 0;
    __syncthreads();
    s[t] += x;
    __syncthreads();
  }
  boff[t] = s[t] - v;                 // exclusive
  if (t == nb - 1) boff[1024] = s[t]; // U = total unique count
}

__global__ void k_rank(const u8* __restrict__ present, const int* __restrict__ boff,
                       const float* __restrict__ pts, int* __restrict__ rank_arr,
                       float* __restrict__ out_query, int N) {
  const int t = threadIdx.x;
  const int n = blockIdx.x * 256 + t;
  bool f = (n < N) && present[n];
  u64 b = __ballot(f);
  __shared__ int ws[4];
  const int wv = t >> 6, lane = t & 63;
  if (lane == 0) ws[wv] = __popcll(b);
  __syncthreads();
  int base = boff[blockIdx.x];
  for (int w = 0; w < wv; ++w) base += ws[w];
  if (f) {
    int rank = base + __popcll(b & ((1ULL << lane) - 1ULL));
    rank_arr[n] = rank;
    float* q = out_query + (size_t)rank * 5;
    const float* p = pts + (size_t)n * 5;
    q[0] = p[0]; q[1] = p[1]; q[2] = p[2]; q[3] = p[3]; q[4] = p[4];
  }
}

// --------- merged: outputs 0 (sampled) + 1 (idx) + query padding rows >= U ------
__global__ void k_outpad(const float* __restrict__ pts, const int* __restrict__ sidx,
                         const int* __restrict__ kcount, const int* __restrict__ rank_arr,
                         const int* __restrict__ uptr,
                         float* __restrict__ out_samp, float* __restrict__ out_idx,
                         float* __restrict__ out_query, int MS, int S) {
  const int e = blockIdx.x * 256 + threadIdx.x;
  if (e >= MS) return;
  const int U = *uptr;
  if (e >= U) {  // pad query rows with points[0] (unique fill_value=0)
    float* q = out_query + (size_t)e * 5;
    q[0] = pts[0]; q[1] = pts[1]; q[2] = pts[2]; q[3] = pts[3]; q[4] = pts[4];
  }
  const int m = e / S;
  const int s = e - m * S;
  float* o = out_samp + (size_t)e * 5;
  if (s < kcount[m]) {
    int n = sidx[e];
    const float* p = pts + (size_t)n * 5;
    o[0] = p[0]; o[1] = p[1]; o[2] = p[2]; o[3] = p[3]; o[4] = p[4];
    out_idx[e] = (float)rank_arr[n];   // idx section read back as f32; exact
  } else {
    o[0] = 0.f; o[1] = 0.f; o[2] = 0.f; o[3] = 0.f; o[4] = 0.f;
    out_idx[e] = 0.f;
  }
}

extern "C" void kernel_launch(void* const* d_in, const int* in_sizes, int n_in,
                              void* d_out, int out_size, void* d_ws, size_t ws_size,
                              hipStream_t stream) {
  const float* pts = (const float*)d_in[0];
  const float* boxes = (const float*)d_in[1];
  const float* pc_start = (const float*)d_in[2];
  const int N = in_sizes[0] / 5;
  const int M = in_sizes[1] / 7;
  const int S = out_size / (M * 11);   // out = M*S*5 + M*S + M*S*5
  const int MS = M * S;

  float* out_samp = (float*)d_out;
  float* out_idx = out_samp + (size_t)MS * 5;
  float* out_query = out_idx + (size_t)MS;

  const int nb = (N + 255) / 256;   // = nchunk; 782 for N=200000 (<=1024 for scans)
  const int nchunk = nb;

  // workspace layout (16B-aligned slices)
  char* w = (char*)d_ws;
  auto take = [&](size_t bytes) {
    char* p = w;
    w += (bytes + 15) & ~(size_t)15;
    return (void*)p;
  };
  u64* vbits     = (u64*)take((size_t)(nb * 4) * 8);
  int* cnt       = (int*)take((size_t)M * nchunk * 4);
  int* off       = (int*)take((size_t)nchunk * M * 4);
  float* cpxg    = (float*)take((size_t)nchunk * 256 * 4);
  float* cpyg    = (float*)take((size_t)nchunk * 256 * 4);
  int* cpng      = (int*)take((size_t)nchunk * 256 * 4);
  int* nflags    = (int*)take((size_t)nchunk * 4);
  int* sidx      = (int*)take((size_t)MS * 4);
  int* kcount    = (int*)take((size_t)M * 4);
  int* rank_arr  = (int*)take((size_t)N * 4);
  int* bsum      = (int*)take((size_t)1024 * 4);
  int* boff      = (int*)take((size_t)1025 * 4);
  u8*  present   = (u8*)take((size_t)N);
  float* qxv     = (float*)take((size_t)M * 4);
  float* qyv     = (float*)take((size_t)M * 4);
  float* rv      = (float*)take((size_t)M * 4);
  int* cellCnt   = (int*)take((size_t)NCX * NCX * 4);
  u16* cellList  = (u16*)take((size_t)NCX * NCX * CAP * 2);

  k_prep<<<1, 256, 0, stream>>>(boxes, pc_start, qxv, qyv, rv, cellCnt, cellList, M);
  k_vmask_count<<<nb, 256, 0, stream>>>(pts, boxes, qxv, qyv, rv, cellCnt, cellList,
                                        vbits, present, cnt, cpxg, cpyg, cpng, nflags,
                                        pc_start, N, M, nchunk);
  k_scanbox<<<M, 1024, 0, stream>>>(cnt, off, kcount, nchunk, M, S);
  k_fillz<<<nchunk + M, 256, 0, stream>>>(pts, boxes, cpxg, cpyg, cpng, nflags, off,
                                          vbits, kcount, sidx, present, N, M, S, nchunk);
  k_bsum<<<nb, 256, 0, stream>>>(present, bsum, N);
  k_scan<<<1, 1024, 0, stream>>>(bsum, boff, nb);
  k_rank<<<nb, 256, 0, stream>>>(present, boff, pts, rank_arr, out_query, N);
  k_outpad<<<(MS + 255) / 256, 256, 0, stream>>>(pts, sidx, kcount, rank_arr, boff + 1024,
                                                 out_samp, out_idx, out_query, MS, S);
}

// Round 5
// 103.758 us; speedup vs baseline: 1.4110x; 1.4110x over previous
//
#include <hip/hip_runtime.h>

typedef unsigned long long u64;
typedef unsigned short u16;
typedef unsigned char u8;

#define VOX 0.4f
#define GAM 1.1f
#define NCX 16        // 16x16 cells
#define CELLW 32.0f   // voxels per cell (power of 2: floor(pvx/32) exact)
#define CAP 64        // max candidate boxes per cell (sentinel fallback if exceeded)

// IEEE f32, no contraction: replicate numpy/jax op-for-op.
__device__ __forceinline__ float dist2d(float ax, float ay, float bx, float by) {
  float dx = __fsub_rn(ax, bx);
  float dy = __fsub_rn(ay, by);
  return __fsqrt_rn(__fadd_rn(__fmul_rn(dx, dx), __fmul_rn(dy, dy)));
}

// metric radius = norm(dims*0.5) * GAMMA
__device__ __forceinline__ float box_radius(const float* __restrict__ boxes, int m) {
  float hx = __fmul_rn(boxes[m * 7 + 3], 0.5f);
  float hy = __fmul_rn(boxes[m * 7 + 4], 0.5f);
  float nr = __fsqrt_rn(__fadd_rn(__fmul_rn(hx, hx), __fmul_rn(hy, hy)));
  return __fmul_rn(nr, GAM);
}

// voxel-space box transform (shared by prep1/prep2 so values are identical)
__device__ __forceinline__ void box_voxel(const float* __restrict__ boxes, int m,
                                          float psx, float psy,
                                          float& qx, float& qy, float& r) {
  qx = __fdiv_rn(__fsub_rn(boxes[m * 7 + 0], psx), VOX);
  qy = __fdiv_rn(__fsub_rn(boxes[m * 7 + 1], psy), VOX);
  float hx = __fmul_rn(boxes[m * 7 + 3], 0.5f);
  float hy = __fmul_rn(boxes[m * 7 + 4], 0.5f);
  float nr = __fsqrt_rn(__fadd_rn(__fmul_rn(hx, hx), __fmul_rn(hy, hy)));
  r = __fdiv_rn(__fmul_rn(nr, GAM), VOX);
}

// ---- prep1 (1 block): voxel-space box arrays (thread = box) ----
__global__ void k_prep1(const float* __restrict__ boxes, const float* __restrict__ pc_start,
                        float* __restrict__ qxv, float* __restrict__ qyv,
                        float* __restrict__ rv, int M) {
  const int m = threadIdx.x;
  if (m < M) {
    float qx, qy, r;
    box_voxel(boxes, m, pc_start[0], pc_start[1], qx, qy, r);
    qxv[m] = qx; qyv[m] = qy; rv[m] = r;
  }
}

// ---- prep2 (block = cell, thread = box): conservative cell->box candidate lists ----
__global__ void k_prep2(const float* __restrict__ boxes, const float* __restrict__ pc_start,
                        int* __restrict__ cellCnt, u16* __restrict__ cellList, int M) {
  const int cell = blockIdx.x;
  const int cx = cell & (NCX - 1), cy = cell >> 4;
  const int tid = threadIdx.x;
  const int wv = tid >> 6, lane = tid & 63;
  __shared__ int wcnt[4];
  const float x0 = (cx == 0) ? -3e38f : cx * CELLW;
  const float x1 = (cx == NCX - 1) ? 3e38f : (cx + 1) * CELLW;
  const float y0 = (cy == 0) ? -3e38f : cy * CELLW;
  const float y1 = (cy == NCX - 1) ? 3e38f : (cy + 1) * CELLW;
  bool hit = false;
  if (tid < M) {
    float qx, qy, r;
    box_voxel(boxes, tid, pc_start[0], pc_start[1], qx, qy, r);
    float ddx = fmaxf(0.0f, fmaxf(x0 - qx, qx - x1));
    float ddy = fmaxf(0.0f, fmaxf(y0 - qy, qy - y1));
    float rr = r + 0.01f;  // conservative margin >> f32 rounding of exact test
    hit = (ddx * ddx + ddy * ddy <= rr * rr);
  }
  u64 b = __ballot(hit);
  if (lane == 0) wcnt[wv] = __popcll(b);
  __syncthreads();
  int base = 0;
  for (int w = 0; w < wv; ++w) base += wcnt[w];
  if (hit) {
    int slot = base + __popcll(b & ((1ULL << lane) - 1ULL));
    if (slot < CAP) cellList[cell * CAP + slot] = (u16)tid;  // ascending m
  }
  if (tid == 0) cellCnt[cell] = wcnt[0] + wcnt[1] + wcnt[2] + wcnt[3];
}

// ---- fused: binned vmask (strict <) + ORDERED compaction + per-(chunk,box) counts
//      chunk == one block == 256 points. cnt layout: box-major [m][c].
__global__ void k_vmask_count(const float* __restrict__ pts, const float* __restrict__ boxes,
                              const float* __restrict__ qxv, const float* __restrict__ qyv,
                              const float* __restrict__ rv,
                              const int* __restrict__ cellCnt, const u16* __restrict__ cellList,
                              u64* __restrict__ vbits, u8* __restrict__ present,
                              int* __restrict__ cnt,
                              float* __restrict__ cpxg, float* __restrict__ cpyg,
                              int* __restrict__ cpng, int* __restrict__ nflags,
                              const float* __restrict__ pc_start,
                              int N, int M, int nchunk) {
  __shared__ float cpx[256], cpy[256];  // compacted flagged points (metric xy)
  __shared__ int cpn[256];              // compacted point indices
  __shared__ int wcnt[4];
  const int tid = threadIdx.x;
  const int blk = blockIdx.x;
  const int n = blk * 256 + tid;
  const int wv = tid >> 6, lane = tid & 63;
  const float psx = pc_start[0], psy = pc_start[1];
  const bool valid = (n < N);
  float px = 1e6f, py = 1e6f, pvx = 0.f, pvy = 0.f;
  if (valid) {
    px = pts[n * 5 + 0];
    py = pts[n * 5 + 1];
    pvx = __fdiv_rn(__fsub_rn(px, psx), VOX);
    pvy = __fdiv_rn(__fsub_rn(py, psy), VOX);
    present[n] = 0;
  }

  // pass 1: vmask via candidate cells; identical IEEE ops as full loop
  bool flag = false;
  if (valid) {
    int cx = (int)floorf(pvx * (1.0f / CELLW));  // exact: /32 power of two
    int cy = (int)floorf(pvy * (1.0f / CELLW));
    cx = cx < 0 ? 0 : (cx > NCX - 1 ? NCX - 1 : cx);
    cy = cy < 0 ? 0 : (cy > NCX - 1 ? NCX - 1 : cy);
    const int cell = cy * NCX + cx;
    const int k = cellCnt[cell];
    if (k <= CAP) {
      for (int j = 0; j < k; ++j) {
        const int m = cellList[cell * CAP + j];
        float d = dist2d(qxv[m], qyv[m], pvx, pvy);
        if (d < rv[m]) { flag = true; break; }  // strict <
      }
    } else {  // sentinel fallback (dormant for this data)
      for (int m = 0; m < M; ++m) {
        float d = dist2d(qxv[m], qyv[m], pvx, pvy);
        if (d < rv[m]) { flag = true; break; }
      }
    }
  }
  u64 b = __ballot(flag);
  if (lane == 0) {
    vbits[n >> 6] = b;
    wcnt[wv] = __popcll(b);
  }
  __syncthreads();

  // ORDERED compaction (ascending n) of flagged points into LDS, then global
  int base = 0;
  for (int w = 0; w < wv; ++w) base += wcnt[w];
  if (flag) {
    int slot = base + __popcll(b & ((1ULL << lane) - 1ULL));
    cpx[slot] = px;
    cpy[slot] = py;
    cpn[slot] = n;
  }
  __syncthreads();
  const int nfl = wcnt[0] + wcnt[1] + wcnt[2] + wcnt[3];
  if (tid == 0) nflags[blk] = nfl;
  if (tid < nfl) {
    cpxg[blk * 256 + tid] = cpx[tid];
    cpyg[blk * 256 + tid] = cpy[tid];
    cpng[blk * 256 + tid] = cpn[tid];
  }

  // pass 2: thread t owns box t (tiled): count metric matches in this chunk
  for (int t0 = 0; t0 < M; t0 += 256) {
    const int bm = t0 + tid;
    if (bm < M) {
      const float bx = boxes[bm * 7 + 0], by = boxes[bm * 7 + 1];
      const float r = box_radius(boxes, bm);
      int c = 0;
      for (int j = 0; j < nfl; ++j) {
        float d = dist2d(bx, by, cpx[j], cpy[j]);
        c += (d <= r) ? 1 : 0;  // metric space, <=
      }
      cnt[bm * nchunk + blk] = c;  // box-major (coalesced reads in scanbox)
    }
  }
}

// ---- per-box exclusive scan over chunk counts (coalesced reads) ----
__global__ void __launch_bounds__(1024) k_scanbox(const int* __restrict__ cnt,
                                                  int* __restrict__ off,
                                                  int* __restrict__ kcount,
                                                  int nchunk, int M, int S) {
  __shared__ int s[1024];
  const int m = blockIdx.x, t = threadIdx.x;
  int v = (t < nchunk) ? cnt[m * nchunk + t] : 0;
  s[t] = v;
  __syncthreads();
  for (int d = 1; d < 1024; d <<= 1) {
    int x = (t >= d) ? s[t - d] : 0;
    __syncthreads();
    s[t] += x;
    __syncthreads();
  }
  if (t < nchunk) off[t * M + m] = s[t] - v;  // exclusive, chunk-major (for fill)
  if (t == 1023) kcount[m] = (s[t] < S) ? s[t] : S;
}

// ---- merged: fill (blocks [0,nchunk)) + zero-fill (blocks [nchunk,nchunk+M)) ----
__global__ void k_fillz(const float* __restrict__ pts, const float* __restrict__ boxes,
                        const float* __restrict__ cpxg, const float* __restrict__ cpyg,
                        const int* __restrict__ cpng, const int* __restrict__ nflags,
                        const int* __restrict__ off, const u64* __restrict__ vbits,
                        const int* __restrict__ kcount,
                        int* __restrict__ sidx, u8* __restrict__ present,
                        int N, int M, int S, int nchunk) {
  __shared__ float sx[256], sy[256];
  __shared__ int sn[256];
  if ((int)blockIdx.x < nchunk) {
    // ---- fill: chunk-major, thread = box, LDS-staged compacted points ----
    const int c = blockIdx.x;
    const int tid = threadIdx.x;
    const int nf = nflags[c];
    if (nf == 0) return;
    if (tid < nf) {
      sx[tid] = cpxg[c * 256 + tid];
      sy[tid] = cpyg[c * 256 + tid];
      sn[tid] = cpng[c * 256 + tid];
    }
    __syncthreads();
    for (int m = tid; m < M; m += 256) {
      int cum = off[c * M + m];
      if (cum >= S) continue;
      const float bx = boxes[m * 7 + 0], by = boxes[m * 7 + 1];
      const float r = box_radius(boxes, m);
      for (int j = 0; j < nf; ++j) {
        float d = dist2d(bx, by, sx[j], sy[j]);
        if (d <= r) {
          int pn = sn[j];
          sidx[m * S + cum] = pn;
          present[pn] = 1;
          if (++cum >= S) break;
        }
      }
    }
  } else {
    // ---- zero-fill: lowest-index non-matches (top_k tie-break among zeros) ----
    const int m = blockIdx.x - nchunk;
    const int k0 = kcount[m];
    if (k0 >= S) return;
    const int lane = threadIdx.x;
    if (lane >= 64) return;
    const float bx = boxes[m * 7 + 0], by = boxes[m * 7 + 1];
    const float r = box_radius(boxes, m);
    const u64 ltmask = (1ULL << lane) - 1ULL;
    const int nwords = (N + 63) >> 6;
    int fill = k0;
    for (int wi = 0; wi < nwords && fill < S; ++wi) {
      const u64 w = vbits[wi];
      const int n = (wi << 6) + lane;
      bool one = false;
      if (n < N && ((w >> lane) & 1ULL)) {
        float d = dist2d(bx, by, pts[n * 5 + 0], pts[n * 5 + 1]);
        one = (d <= r);
      }
      const bool z = (n < N) && !one;
      u64 b = __ballot(z);
      if (z) {
        int pos = fill + __popcll(b & ltmask);
        if (pos < S) { sidx[m * S + pos] = n; present[n] = 1; }
      }
      fill += __popcll(b);
    }
  }
}

// ------------------------- presence scan (rank = inverse) ----------------------
__global__ void k_bsum(const u8* __restrict__ present, int* __restrict__ bsum, int N) {
  const int n = blockIdx.x * 256 + threadIdx.x;
  bool f = (n < N) && present[n];
  u64 b = __ballot(f);
  __shared__ int ws[4];
  if ((threadIdx.x & 63) == 0) ws[threadIdx.x >> 6] = __popcll(b);
  __syncthreads();
  if (threadIdx.x == 0) bsum[blockIdx.x] = ws[0] + ws[1] + ws[2] + ws[3];
}

__global__ void __launch_bounds__(1024) k_scan(const int* __restrict__ bsum,
                                               int* __restrict__ boff, int nb) {
  __shared__ int s[1024];
  const int t = threadIdx.x;
  int v = (t < nb) ? bsum[t] : 0;
  s[t] = v;
  __syncthreads();
  for (int d = 1; d < 1024; d <<= 1) {
    int x = (t >= d) ? s[t - d] : 0;
    __syncthreads();
    s[t] += x;
    __syncthreads();
  }
  boff[t] = s[t] - v;                 // exclusive
  if (t == nb - 1) boff[1024] = s[t]; // U = total unique count
}

__global__ void k_rank(const u8* __restrict__ present, const int* __restrict__ boff,
                       const float* __restrict__ pts, int* __restrict__ rank_arr,
                       float* __restrict__ out_query, int N) {
  const int t = threadIdx.x;
  const int n = blockIdx.x * 256 + t;
  bool f = (n < N) && present[n];
  u64 b = __ballot(f);
  __shared__ int ws[4];
  const int wv = t >> 6, lane = t & 63;
  if (lane == 0) ws[wv] = __popcll(b);
  __syncthreads();
  int base = boff[blockIdx.x];
  for (int w = 0; w < wv; ++w) base += ws[w];
  if (f) {
    int rank = base + __popcll(b & ((1ULL << lane) - 1ULL));
    rank_arr[n] = rank;
    float* q = out_query + (size_t)rank * 5;
    const float* p = pts + (size_t)n * 5;
    q[0] = p[0]; q[1] = p[1]; q[2] = p[2]; q[3] = p[3]; q[4] = p[4];
  }
}

// --------- merged: outputs 0 (sampled) + 1 (idx) + query padding rows >= U ------
__global__ void k_outpad(const float* __restrict__ pts, const int* __restrict__ sidx,
                         const int* __restrict__ kcount, const int* __restrict__ rank_arr,
                         const int* __restrict__ uptr,
                         float* __restrict__ out_samp, float* __restrict__ out_idx,
                         float* __restrict__ out_query, int MS, int S) {
  const int e = blockIdx.x * 256 + threadIdx.x;
  if (e >= MS) return;
  const int U = *uptr;
  if (e >= U) {  // pad query rows with points[0] (unique fill_value=0)
    float* q = out_query + (size_t)e * 5;
    q[0] = pts[0]; q[1] = pts[1]; q[2] = pts[2]; q[3] = pts[3]; q[4] = pts[4];
  }
  const int m = e / S;
  const int s = e - m * S;
  float* o = out_samp + (size_t)e * 5;
  if (s < kcount[m]) {
    int n = sidx[e];
    const float* p = pts + (size_t)n * 5;
    o[0] = p[0]; o[1] = p[1]; o[2] = p[2]; o[3] = p[3]; o[4] = p[4];
    out_idx[e] = (float)rank_arr[n];   // idx section read back as f32; exact
  } else {
    o[0] = 0.f; o[1] = 0.f; o[2] = 0.f; o[3] = 0.f; o[4] = 0.f;
    out_idx[e] = 0.f;
  }
}

extern "C" void kernel_launch(void* const* d_in, const int* in_sizes, int n_in,
                              void* d_out, int out_size, void* d_ws, size_t ws_size,
                              hipStream_t stream) {
  const float* pts = (const float*)d_in[0];
  const float* boxes = (const float*)d_in[1];
  const float* pc_start = (const float*)d_in[2];
  const int N = in_sizes[0] / 5;
  const int M = in_sizes[1] / 7;
  const int S = out_size / (M * 11);   // out = M*S*5 + M*S + M*S*5
  const int MS = M * S;

  float* out_samp = (float*)d_out;
  float* out_idx = out_samp + (size_t)MS * 5;
  float* out_query = out_idx + (size_t)MS;

  const int nb = (N + 255) / 256;   // = nchunk; 782 for N=200000 (<=1024 for scans)
  const int nchunk = nb;

  // workspace layout (16B-aligned slices)
  char* w = (char*)d_ws;
  auto take = [&](size_t bytes) {
    char* p = w;
    w += (bytes + 15) & ~(size_t)15;
    return (void*)p;
  };
  u64* vbits     = (u64*)take((size_t)(nb * 4) * 8);
  int* cnt       = (int*)take((size_t)M * nchunk * 4);
  int* off       = (int*)take((size_t)nchunk * M * 4);
  float* cpxg    = (float*)take((size_t)nchunk * 256 * 4);
  float* cpyg    = (float*)take((size_t)nchunk * 256 * 4);
  int* cpng      = (int*)take((size_t)nchunk * 256 * 4);
  int* nflags    = (int*)take((size_t)nchunk * 4);
  int* sidx      = (int*)take((size_t)MS * 4);
  int* kcount    = (int*)take((size_t)M * 4);
  int* rank_arr  = (int*)take((size_t)N * 4);
  int* bsum      = (int*)take((size_t)1024 * 4);
  int* boff      = (int*)take((size_t)1025 * 4);
  u8*  present   = (u8*)take((size_t)N);
  float* qxv     = (float*)take((size_t)M * 4);
  float* qyv     = (float*)take((size_t)M * 4);
  float* rv      = (float*)take((size_t)M * 4);
  int* cellCnt   = (int*)take((size_t)NCX * NCX * 4);
  u16* cellList  = (u16*)take((size_t)NCX * NCX * CAP * 2);

  k_prep1<<<1, 256, 0, stream>>>(boxes, pc_start, qxv, qyv, rv, M);
  k_prep2<<<NCX * NCX, 256, 0, stream>>>(boxes, pc_start, cellCnt, cellList, M);
  k_vmask_count<<<nb, 256, 0, stream>>>(pts, boxes, qxv, qyv, rv, cellCnt, cellList,
                                        vbits, present, cnt, cpxg, cpyg, cpng, nflags,
                                        pc_start, N, M, nchunk);
  k_scanbox<<<M, 1024, 0, stream>>>(cnt, off, kcount, nchunk, M, S);
  k_fillz<<<nchunk + M, 256, 0, stream>>>(pts, boxes, cpxg, cpyg, cpng, nflags, off,
                                          vbits, kcount, sidx, present, N, M, S, nchunk);
  k_bsum<<<nb, 256, 0, stream>>>(present, bsum, N);
  k_scan<<<1, 1024, 0, stream>>>(bsum, boff, nb);
  k_rank<<<nb, 256, 0, stream>>>(present, boff, pts, rank_arr, out_query, N);
  k_outpad<<<(MS + 255) / 256, 256, 0, stream>>>(pts, sidx, kcount, rank_arr, boff + 1024,
                                                 out_samp, out_idx, out_query, MS, S);
}

// Round 6
// 95.556 us; speedup vs baseline: 1.5321x; 1.0858x over previous
//
#include <hip/hip_runtime.h>

typedef unsigned long long u64;
typedef unsigned short u16;
typedef unsigned char u8;

#define VOX 0.4f
#define GAM 1.1f
#define NCX 16        // 16x16 cells
#define CELLW 32.0f   // voxels per cell (power of 2: floor(pvx/32) exact)
#define CAP 64        // max candidate boxes per cell (sentinel fallback if exceeded)

// IEEE f32, no contraction: replicate numpy/jax op-for-op.
__device__ __forceinline__ float dist2d(float ax, float ay, float bx, float by) {
  float dx = __fsub_rn(ax, bx);
  float dy = __fsub_rn(ay, by);
  return __fsqrt_rn(__fadd_rn(__fmul_rn(dx, dx), __fmul_rn(dy, dy)));
}

// metric radius = norm(dims*0.5) * GAMMA
__device__ __forceinline__ float box_radius(const float* __restrict__ boxes, int m) {
  float hx = __fmul_rn(boxes[m * 7 + 3], 0.5f);
  float hy = __fmul_rn(boxes[m * 7 + 4], 0.5f);
  float nr = __fsqrt_rn(__fadd_rn(__fmul_rn(hx, hx), __fmul_rn(hy, hy)));
  return __fmul_rn(nr, GAM);
}

// voxel-space box transform (shared so values are identical everywhere)
__device__ __forceinline__ void box_voxel(const float* __restrict__ boxes, int m,
                                          float psx, float psy,
                                          float& qx, float& qy, float& r) {
  qx = __fdiv_rn(__fsub_rn(boxes[m * 7 + 0], psx), VOX);
  qy = __fdiv_rn(__fsub_rn(boxes[m * 7 + 1], psy), VOX);
  float hx = __fmul_rn(boxes[m * 7 + 3], 0.5f);
  float hy = __fmul_rn(boxes[m * 7 + 4], 0.5f);
  float nr = __fsqrt_rn(__fadd_rn(__fmul_rn(hx, hx), __fmul_rn(hy, hy)));
  r = __fdiv_rn(__fmul_rn(nr, GAM), VOX);
}

// ---- merged prep: block 0 -> voxel box arrays; blocks 1.. -> cell candidate lists
__global__ void k_prep(const float* __restrict__ boxes, const float* __restrict__ pc_start,
                       float* __restrict__ qxv, float* __restrict__ qyv, float* __restrict__ rv,
                       int* __restrict__ cellCnt, u16* __restrict__ cellList, int M) {
  const int tid = threadIdx.x;
  if (blockIdx.x == 0) {
    for (int m = tid; m < M; m += 256) {
      float qx, qy, r;
      box_voxel(boxes, m, pc_start[0], pc_start[1], qx, qy, r);
      qxv[m] = qx; qyv[m] = qy; rv[m] = r;
    }
    return;
  }
  const int cell = blockIdx.x - 1;
  const int cx = cell & (NCX - 1), cy = cell >> 4;
  const int wv = tid >> 6, lane = tid & 63;
  __shared__ int wcnt[4];
  const float x0 = (cx == 0) ? -3e38f : cx * CELLW;
  const float x1 = (cx == NCX - 1) ? 3e38f : (cx + 1) * CELLW;
  const float y0 = (cy == 0) ? -3e38f : cy * CELLW;
  const float y1 = (cy == NCX - 1) ? 3e38f : (cy + 1) * CELLW;
  bool hit = false;
  if (tid < M) {
    float qx, qy, r;
    box_voxel(boxes, tid, pc_start[0], pc_start[1], qx, qy, r);
    float ddx = fmaxf(0.0f, fmaxf(x0 - qx, qx - x1));
    float ddy = fmaxf(0.0f, fmaxf(y0 - qy, qy - y1));
    float rr = r + 0.01f;  // conservative margin >> f32 rounding of exact test chain
    hit = (ddx * ddx + ddy * ddy <= rr * rr);
  }
  u64 b = __ballot(hit);
  if (lane == 0) wcnt[wv] = __popcll(b);
  __syncthreads();
  int base = 0;
  for (int w = 0; w < wv; ++w) base += wcnt[w];
  if (hit) {
    int slot = base + __popcll(b & ((1ULL << lane) - 1ULL));
    if (slot < CAP) cellList[cell * CAP + slot] = (u16)tid;  // ascending m
  }
  if (tid == 0) cellCnt[cell] = wcnt[0] + wcnt[1] + wcnt[2] + wcnt[3];
}

// ---- fused: binned vmask (strict <) + ORDERED compaction + per-(chunk,box) match
//      BITMAP via point-centric candidate tests. chunk == one block == 256 points.
__global__ void k_vmask_count(const float* __restrict__ pts, const float* __restrict__ boxes,
                              const float* __restrict__ qxv, const float* __restrict__ qyv,
                              const float* __restrict__ rv,
                              const int* __restrict__ cellCnt, const u16* __restrict__ cellList,
                              u64* __restrict__ vbits, u8* __restrict__ present,
                              int* __restrict__ cnt, u64* __restrict__ bmG,
                              int* __restrict__ cpng,
                              const float* __restrict__ pc_start,
                              int N, int M, int nchunk) {
  __shared__ float cpx[256], cpy[256];          // compacted flagged points (metric xy)
  __shared__ int cpn[256];                      // compacted point indices
  __shared__ float sbx[256], sby[256], sbr[256];// metric box centers/radii
  __shared__ u64 bm[256][4];                    // per-box match bitmap over 256 slots
  __shared__ int wcnt[4];
  const int tid = threadIdx.x;
  const int blk = blockIdx.x;
  const int n = blk * 256 + tid;
  const int wv = tid >> 6, lane = tid & 63;
  const float psx = pc_start[0], psy = pc_start[1];
  const bool valid = (n < N);

  bm[tid][0] = 0; bm[tid][1] = 0; bm[tid][2] = 0; bm[tid][3] = 0;
  if (tid < M) {
    sbx[tid] = boxes[tid * 7 + 0];
    sby[tid] = boxes[tid * 7 + 1];
    sbr[tid] = box_radius(boxes, tid);
  }

  float px = 1e6f, py = 1e6f, pvx = 0.f, pvy = 0.f;
  if (valid) {
    px = pts[n * 5 + 0];
    py = pts[n * 5 + 1];
    pvx = __fdiv_rn(__fsub_rn(px, psx), VOX);
    pvy = __fdiv_rn(__fsub_rn(py, psy), VOX);
    present[n] = 0;
  }

  // pass 1: vmask via candidate cells; identical IEEE ops as full loop
  bool flag = false;
  if (valid) {
    int cx = (int)floorf(pvx * (1.0f / CELLW));  // exact: /32 power of two
    int cy = (int)floorf(pvy * (1.0f / CELLW));
    cx = cx < 0 ? 0 : (cx > NCX - 1 ? NCX - 1 : cx);
    cy = cy < 0 ? 0 : (cy > NCX - 1 ? NCX - 1 : cy);
    const int cell = cy * NCX + cx;
    const int k = cellCnt[cell];
    if (k <= CAP) {
      for (int j = 0; j < k; ++j) {
        const int m = cellList[cell * CAP + j];
        float d = dist2d(qxv[m], qyv[m], pvx, pvy);
        if (d < rv[m]) { flag = true; break; }  // strict <
      }
    } else {  // sentinel fallback (dormant for this data)
      for (int m = 0; m < M; ++m) {
        float d = dist2d(qxv[m], qyv[m], pvx, pvy);
        if (d < rv[m]) { flag = true; break; }
      }
    }
  }
  u64 b = __ballot(flag);
  if (lane == 0) {
    vbits[n >> 6] = b;
    wcnt[wv] = __popcll(b);
  }
  __syncthreads();

  // ORDERED compaction (ascending n) of flagged points into LDS
  int base = 0;
  for (int w = 0; w < wv; ++w) base += wcnt[w];
  if (flag) {
    int slot = base + __popcll(b & ((1ULL << lane) - 1ULL));
    cpx[slot] = px;
    cpy[slot] = py;
    cpn[slot] = n;
  }
  __syncthreads();
  const int nfl = wcnt[0] + wcnt[1] + wcnt[2] + wcnt[3];
  if (tid < nfl) cpng[blk * 256 + tid] = cpn[tid];

  // pass 2: point-centric metric tests against the point's cell candidates.
  // Exact: metric match d<=r implies voxel dist <= rv + ~1e-4 << 0.01 margin,
  // so the candidate list provably contains every metric-matching box.
  if (tid < nfl) {
    const float mx = cpx[tid], my = cpy[tid];
    float vx = __fdiv_rn(__fsub_rn(mx, psx), VOX);  // identical chain -> same cell
    float vy = __fdiv_rn(__fsub_rn(my, psy), VOX);
    int cx = (int)floorf(vx * (1.0f / CELLW));
    int cy = (int)floorf(vy * (1.0f / CELLW));
    cx = cx < 0 ? 0 : (cx > NCX - 1 ? NCX - 1 : cx);
    cy = cy < 0 ? 0 : (cy > NCX - 1 ? NCX - 1 : cy);
    const int cell = cy * NCX + cx;
    const int k = cellCnt[cell];
    const u64 bit = 1ULL << (tid & 63);
    const int word = tid >> 6;
    if (k <= CAP) {
      for (int j = 0; j < k; ++j) {
        const int m = cellList[cell * CAP + j];
        float d = dist2d(sbx[m], sby[m], mx, my);
        if (d <= sbr[m]) atomicOr(&bm[m][word], bit);  // metric space, <=
      }
    } else {  // fallback: test all boxes (dormant)
      for (int m = 0; m < M; ++m) {
        float d = dist2d(sbx[m], sby[m], mx, my);
        if (d <= sbr[m]) atomicOr(&bm[m][word], bit);
      }
    }
  }
  __syncthreads();

  // dump bitmap + counts (thread = box)
  if (tid < M) {
    u64 w0 = bm[tid][0], w1 = bm[tid][1], w2 = bm[tid][2], w3 = bm[tid][3];
    u64* dst = bmG + ((size_t)blk * M + tid) * 4;
    dst[0] = w0; dst[1] = w1; dst[2] = w2; dst[3] = w3;
    cnt[tid * nchunk + blk] =
        __popcll(w0) + __popcll(w1) + __popcll(w2) + __popcll(w3);
  }
}

// ---- per-box exclusive scan over chunk counts (coalesced reads) ----
__global__ void __launch_bounds__(1024) k_scanbox(const int* __restrict__ cnt,
                                                  int* __restrict__ off,
                                                  int* __restrict__ kcount,
                                                  int nchunk, int M, int S) {
  __shared__ int s[1024];
  const int m = blockIdx.x, t = threadIdx.x;
  int v = (t < nchunk) ? cnt[m * nchunk + t] : 0;
  s[t] = v;
  __syncthreads();
  for (int d = 1; d < 1024; d <<= 1) {
    int x = (t >= d) ? s[t - d] : 0;
    __syncthreads();
    s[t] += x;
    __syncthreads();
  }
  if (t < nchunk) off[t * M + m] = s[t] - v;  // exclusive, chunk-major (for fill)
  if (t == 1023) kcount[m] = (s[t] < S) ? s[t] : S;
}

// ---- merged: bitmap-driven fill (blocks [0,nchunk)) + zero-fill ([nchunk,+M)) ----
__global__ void k_fillz(const float* __restrict__ pts, const float* __restrict__ boxes,
                        const u64* __restrict__ bmG, const int* __restrict__ cpng,
                        const int* __restrict__ off, const u64* __restrict__ vbits,
                        const int* __restrict__ kcount,
                        int* __restrict__ sidx, u8* __restrict__ present,
                        int N, int M, int S, int nchunk) {
  if ((int)blockIdx.x < nchunk) {
    // ---- fill: thread = box; walk this chunk's match bitmap, no distance tests ----
    const int c = blockIdx.x;
    const int m = threadIdx.x;
    if (m >= M) return;
    const u64* bp = bmG + ((size_t)c * M + m) * 4;
    u64 w0 = bp[0], w1 = bp[1], w2 = bp[2], w3 = bp[3];
    if (!(w0 | w1 | w2 | w3)) return;
    int cum = off[c * M + m];
    if (cum >= S) return;
    const int* pbase = cpng + c * 256;
    u64 ws[4] = {w0, w1, w2, w3};
    for (int wi = 0; wi < 4 && cum < S; ++wi) {
      u64 w = ws[wi];
      while (w && cum < S) {
        int j = (wi << 6) + __builtin_ctzll(w);  // ascending slot = ascending n
        w &= w - 1;
        int pn = pbase[j];
        sidx[m * S + cum] = pn;
        present[pn] = 1;
        ++cum;
      }
    }
  } else {
    // ---- zero-fill: lowest-index non-matches (top_k tie-break among zeros) ----
    const int m = blockIdx.x - nchunk;
    const int k0 = kcount[m];
    if (k0 >= S) return;
    const int lane = threadIdx.x;
    if (lane >= 64) return;
    const float bx = boxes[m * 7 + 0], by = boxes[m * 7 + 1];
    const float r = box_radius(boxes, m);
    const u64 ltmask = (1ULL << lane) - 1ULL;
    const int nwords = (N + 63) >> 6;
    int fill = k0;
    for (int wi = 0; wi < nwords && fill < S; ++wi) {
      const u64 w = vbits[wi];
      const int n = (wi << 6) + lane;
      bool one = false;
      if (n < N && ((w >> lane) & 1ULL)) {
        float d = dist2d(bx, by, pts[n * 5 + 0], pts[n * 5 + 1]);
        one = (d <= r);
      }
      const bool z = (n < N) && !one;
      u64 b = __ballot(z);
      if (z) {
        int pos = fill + __popcll(b & ltmask);
        if (pos < S) { sidx[m * S + pos] = n; present[n] = 1; }
      }
      fill += __popcll(b);
    }
  }
}

// ------------------------- presence scan (rank = inverse) ----------------------
__global__ void k_bsum(const u8* __restrict__ present, int* __restrict__ bsum, int N) {
  const int n = blockIdx.x * 256 + threadIdx.x;
  bool f = (n < N) && present[n];
  u64 b = __ballot(f);
  __shared__ int ws[4];
  if ((threadIdx.x & 63) == 0) ws[threadIdx.x >> 6] = __popcll(b);
  __syncthreads();
  if (threadIdx.x == 0) bsum[blockIdx.x] = ws[0] + ws[1] + ws[2] + ws[3];
}

__global__ void __launch_bounds__(1024) k_scan(const int* __restrict__ bsum,
                                               int* __restrict__ boff, int nb) {
  __shared__ int s[1024];
  const int t = threadIdx.x;
  int v = (t < nb) ? bsum[t] : 0;
  s[t] = v;
  __syncthreads();
  for (int d = 1; d < 1024; d <<= 1) {
    int x = (t >= d) ? s[t - d] : 0;
    __syncthreads();
    s[t] += x;
    __syncthreads();
  }
  boff[t] = s[t] - v;                 // exclusive
  if (t == nb - 1) boff[1024] = s[t]; // U = total unique count
}

__global__ void k_rank(const u8* __restrict__ present, const int* __restrict__ boff,
                       const float* __restrict__ pts, int* __restrict__ rank_arr,
                       float* __restrict__ out_query, int N) {
  const int t = threadIdx.x;
  const int n = blockIdx.x * 256 + t;
  bool f = (n < N) && present[n];
  u64 b = __ballot(f);
  __shared__ int ws[4];
  const int wv = t >> 6, lane = t & 63;
  if (lane == 0) ws[wv] = __popcll(b);
  __syncthreads();
  int base = boff[blockIdx.x];
  for (int w = 0; w < wv; ++w) base += ws[w];
  if (f) {
    int rank = base + __popcll(b & ((1ULL << lane) - 1ULL));
    rank_arr[n] = rank;
    float* q = out_query + (size_t)rank * 5;
    const float* p = pts + (size_t)n * 5;
    q[0] = p[0]; q[1] = p[1]; q[2] = p[2]; q[3] = p[3]; q[4] = p[4];
  }
}

// --------- merged: outputs 0 (sampled) + 1 (idx) + query padding rows >= U ------
__global__ void k_outpad(const float* __restrict__ pts, const int* __restrict__ sidx,
                         const int* __restrict__ kcount, const int* __restrict__ rank_arr,
                         const int* __restrict__ uptr,
                         float* __restrict__ out_samp, float* __restrict__ out_idx,
                         float* __restrict__ out_query, int MS, int S) {
  const int e = blockIdx.x * 256 + threadIdx.x;
  if (e >= MS) return;
  const int U = *uptr;
  if (e >= U) {  // pad query rows with points[0] (unique fill_value=0)
    float* q = out_query + (size_t)e * 5;
    q[0] = pts[0]; q[1] = pts[1]; q[2] = pts[2]; q[3] = pts[3]; q[4] = pts[4];
  }
  const int m = e / S;
  const int s = e - m * S;
  float* o = out_samp + (size_t)e * 5;
  if (s < kcount[m]) {
    int n = sidx[e];
    const float* p = pts + (size_t)n * 5;
    o[0] = p[0]; o[1] = p[1]; o[2] = p[2]; o[3] = p[3]; o[4] = p[4];
    out_idx[e] = (float)rank_arr[n];   // idx section read back as f32; exact
  } else {
    o[0] = 0.f; o[1] = 0.f; o[2] = 0.f; o[3] = 0.f; o[4] = 0.f;
    out_idx[e] = 0.f;
  }
}

extern "C" void kernel_launch(void* const* d_in, const int* in_sizes, int n_in,
                              void* d_out, int out_size, void* d_ws, size_t ws_size,
                              hipStream_t stream) {
  const float* pts = (const float*)d_in[0];
  const float* boxes = (const float*)d_in[1];
  const float* pc_start = (const float*)d_in[2];
  const int N = in_sizes[0] / 5;
  const int M = in_sizes[1] / 7;
  const int S = out_size / (M * 11);   // out = M*S*5 + M*S + M*S*5
  const int MS = M * S;

  float* out_samp = (float*)d_out;
  float* out_idx = out_samp + (size_t)MS * 5;
  float* out_query = out_idx + (size_t)MS;

  const int nb = (N + 255) / 256;   // = nchunk; 782 for N=200000 (<=1024 for scans)
  const int nchunk = nb;

  // workspace layout (16B-aligned slices)
  char* w = (char*)d_ws;
  auto take = [&](size_t bytes) {
    char* p = w;
    w += (bytes + 15) & ~(size_t)15;
    return (void*)p;
  };
  u64* vbits     = (u64*)take((size_t)(nb * 4) * 8);
  int* cnt       = (int*)take((size_t)M * nchunk * 4);
  int* off       = (int*)take((size_t)nchunk * M * 4);
  u64* bmG       = (u64*)take((size_t)nchunk * M * 4 * 8);
  int* cpng      = (int*)take((size_t)nchunk * 256 * 4);
  int* sidx      = (int*)take((size_t)MS * 4);
  int* kcount    = (int*)take((size_t)M * 4);
  int* rank_arr  = (int*)take((size_t)N * 4);
  int* bsum      = (int*)take((size_t)1024 * 4);
  int* boff      = (int*)take((size_t)1025 * 4);
  u8*  present   = (u8*)take((size_t)N);
  float* qxv     = (float*)take((size_t)M * 4);
  float* qyv     = (float*)take((size_t)M * 4);
  float* rv      = (float*)take((size_t)M * 4);
  int* cellCnt   = (int*)take((size_t)NCX * NCX * 4);
  u16* cellList  = (u16*)take((size_t)NCX * NCX * CAP * 2);

  k_prep<<<NCX * NCX + 1, 256, 0, stream>>>(boxes, pc_start, qxv, qyv, rv,
                                            cellCnt, cellList, M);
  k_vmask_count<<<nb, 256, 0, stream>>>(pts, boxes, qxv, qyv, rv, cellCnt, cellList,
                                        vbits, present, cnt, bmG, cpng,
                                        pc_start, N, M, nchunk);
  k_scanbox<<<M, 1024, 0, stream>>>(cnt, off, kcount, nchunk, M, S);
  k_fillz<<<nchunk + M, 256, 0, stream>>>(pts, boxes, bmG, cpng, off,
                                          vbits, kcount, sidx, present, N, M, S, nchunk);
  k_bsum<<<nb, 256, 0, stream>>>(present, bsum, N);
  k_scan<<<1, 1024, 0, stream>>>(bsum, boff, nb);
  k_rank<<<nb, 256, 0, stream>>>(present, boff, pts, rank_arr, out_query, N);
  k_outpad<<<(MS + 255) / 256, 256, 0, stream>>>(pts, sidx, kcount, rank_arr, boff + 1024,
                                                 out_samp, out_idx, out_query, MS, S);
}

// Round 7
// 94.769 us; speedup vs baseline: 1.5448x; 1.0083x over previous
//
#include <hip/hip_runtime.h>

typedef unsigned long long u64;
typedef unsigned short u16;
typedef unsigned char u8;

#define VOX 0.4f
#define GAM 1.1f
#define NCX 16        // 16x16 cells
#define CELLW 32.0f   // voxels per cell (power of 2: floor(pvx/32) exact)
#define CAP 64        // max candidate boxes per cell (sentinel fallback if exceeded)

// IEEE f32, no contraction: replicate numpy/jax op-for-op.
__device__ __forceinline__ float dist2d(float ax, float ay, float bx, float by) {
  float dx = __fsub_rn(ax, bx);
  float dy = __fsub_rn(ay, by);
  return __fsqrt_rn(__fadd_rn(__fmul_rn(dx, dx), __fmul_rn(dy, dy)));
}

// metric radius = norm(dims*0.5) * GAMMA
__device__ __forceinline__ float box_radius(const float* __restrict__ boxes, int m) {
  float hx = __fmul_rn(boxes[m * 7 + 3], 0.5f);
  float hy = __fmul_rn(boxes[m * 7 + 4], 0.5f);
  float nr = __fsqrt_rn(__fadd_rn(__fmul_rn(hx, hx), __fmul_rn(hy, hy)));
  return __fmul_rn(nr, GAM);
}

// voxel-space box transform (shared so values are identical everywhere)
__device__ __forceinline__ void box_voxel(const float* __restrict__ boxes, int m,
                                          float psx, float psy,
                                          float& qx, float& qy, float& r) {
  qx = __fdiv_rn(__fsub_rn(boxes[m * 7 + 0], psx), VOX);
  qy = __fdiv_rn(__fsub_rn(boxes[m * 7 + 1], psy), VOX);
  float hx = __fmul_rn(boxes[m * 7 + 3], 0.5f);
  float hy = __fmul_rn(boxes[m * 7 + 4], 0.5f);
  float nr = __fsqrt_rn(__fadd_rn(__fmul_rn(hx, hx), __fmul_rn(hy, hy)));
  r = __fdiv_rn(__fmul_rn(nr, GAM), VOX);
}

// ---- merged prep: block 0 -> voxel box arrays; blocks 1.. -> cell candidate lists
__global__ void k_prep(const float* __restrict__ boxes, const float* __restrict__ pc_start,
                       float* __restrict__ qxv, float* __restrict__ qyv, float* __restrict__ rv,
                       int* __restrict__ cellCnt, u16* __restrict__ cellList, int M) {
  const int tid = threadIdx.x;
  if (blockIdx.x == 0) {
    for (int m = tid; m < M; m += 256) {
      float qx, qy, r;
      box_voxel(boxes, m, pc_start[0], pc_start[1], qx, qy, r);
      qxv[m] = qx; qyv[m] = qy; rv[m] = r;
    }
    return;
  }
  const int cell = blockIdx.x - 1;
  const int cx = cell & (NCX - 1), cy = cell >> 4;
  const int wv = tid >> 6, lane = tid & 63;
  __shared__ int wcnt[4];
  const float x0 = (cx == 0) ? -3e38f : cx * CELLW;
  const float x1 = (cx == NCX - 1) ? 3e38f : (cx + 1) * CELLW;
  const float y0 = (cy == 0) ? -3e38f : cy * CELLW;
  const float y1 = (cy == NCX - 1) ? 3e38f : (cy + 1) * CELLW;
  bool hit = false;
  if (tid < M) {
    float qx, qy, r;
    box_voxel(boxes, tid, pc_start[0], pc_start[1], qx, qy, r);
    float ddx = fmaxf(0.0f, fmaxf(x0 - qx, qx - x1));
    float ddy = fmaxf(0.0f, fmaxf(y0 - qy, qy - y1));
    float rr = r + 0.01f;  // conservative margin >> f32 rounding of exact test chain
    hit = (ddx * ddx + ddy * ddy <= rr * rr);
  }
  u64 b = __ballot(hit);
  if (lane == 0) wcnt[wv] = __popcll(b);
  __syncthreads();
  int base = 0;
  for (int w = 0; w < wv; ++w) base += wcnt[w];
  if (hit) {
    int slot = base + __popcll(b & ((1ULL << lane) - 1ULL));
    if (slot < CAP) cellList[cell * CAP + slot] = (u16)tid;  // ascending m
  }
  if (tid == 0) cellCnt[cell] = wcnt[0] + wcnt[1] + wcnt[2] + wcnt[3];
}

// ---- fused: binned vmask (strict <) + ORDERED compaction + per-(chunk,box) match
//      BITMAP via point-centric candidate tests. chunk == one block == 256 points.
__global__ void k_vmask_count(const float* __restrict__ pts, const float* __restrict__ boxes,
                              const float* __restrict__ qxv, const float* __restrict__ qyv,
                              const float* __restrict__ rv,
                              const int* __restrict__ cellCnt, const u16* __restrict__ cellList,
                              u64* __restrict__ vbits, u8* __restrict__ present,
                              u64* __restrict__ bmG, int* __restrict__ cpng,
                              const float* __restrict__ pc_start,
                              int N, int M) {
  __shared__ float cpx[256], cpy[256];          // compacted flagged points (metric xy)
  __shared__ int cpn[256];                      // compacted point indices
  __shared__ float sbx[256], sby[256], sbr[256];// metric box centers/radii
  __shared__ u64 bm[256][4];                    // per-box match bitmap over 256 slots
  __shared__ int wcnt[4];
  const int tid = threadIdx.x;
  const int blk = blockIdx.x;
  const int n = blk * 256 + tid;
  const int wv = tid >> 6, lane = tid & 63;
  const float psx = pc_start[0], psy = pc_start[1];
  const bool valid = (n < N);

  bm[tid][0] = 0; bm[tid][1] = 0; bm[tid][2] = 0; bm[tid][3] = 0;
  if (tid < M) {
    sbx[tid] = boxes[tid * 7 + 0];
    sby[tid] = boxes[tid * 7 + 1];
    sbr[tid] = box_radius(boxes, tid);
  }

  float px = 1e6f, py = 1e6f, pvx = 0.f, pvy = 0.f;
  if (valid) {
    px = pts[n * 5 + 0];
    py = pts[n * 5 + 1];
    pvx = __fdiv_rn(__fsub_rn(px, psx), VOX);
    pvy = __fdiv_rn(__fsub_rn(py, psy), VOX);
    present[n] = 0;
  }

  // pass 1: vmask via candidate cells; identical IEEE ops as full loop
  bool flag = false;
  if (valid) {
    int cx = (int)floorf(pvx * (1.0f / CELLW));  // exact: /32 power of two
    int cy = (int)floorf(pvy * (1.0f / CELLW));
    cx = cx < 0 ? 0 : (cx > NCX - 1 ? NCX - 1 : cx);
    cy = cy < 0 ? 0 : (cy > NCX - 1 ? NCX - 1 : cy);
    const int cell = cy * NCX + cx;
    const int k = cellCnt[cell];
    if (k <= CAP) {
      for (int j = 0; j < k; ++j) {
        const int m = cellList[cell * CAP + j];
        float d = dist2d(qxv[m], qyv[m], pvx, pvy);
        if (d < rv[m]) { flag = true; break; }  // strict <
      }
    } else {  // sentinel fallback (dormant for this data)
      for (int m = 0; m < M; ++m) {
        float d = dist2d(qxv[m], qyv[m], pvx, pvy);
        if (d < rv[m]) { flag = true; break; }
      }
    }
  }
  u64 b = __ballot(flag);
  if (lane == 0) {
    vbits[n >> 6] = b;
    wcnt[wv] = __popcll(b);
  }
  __syncthreads();

  // ORDERED compaction (ascending n) of flagged points into LDS
  int base = 0;
  for (int w = 0; w < wv; ++w) base += wcnt[w];
  if (flag) {
    int slot = base + __popcll(b & ((1ULL << lane) - 1ULL));
    cpx[slot] = px;
    cpy[slot] = py;
    cpn[slot] = n;
  }
  __syncthreads();
  const int nfl = wcnt[0] + wcnt[1] + wcnt[2] + wcnt[3];
  if (tid < nfl) cpng[blk * 256 + tid] = cpn[tid];

  // pass 2: point-centric metric tests against the point's cell candidates.
  // Exact: metric match d<=r implies voxel dist <= rv + ~1e-4 << 0.01 margin,
  // so the candidate list provably contains every metric-matching box.
  if (tid < nfl) {
    const float mx = cpx[tid], my = cpy[tid];
    float vx = __fdiv_rn(__fsub_rn(mx, psx), VOX);  // identical chain -> same cell
    float vy = __fdiv_rn(__fsub_rn(my, psy), VOX);
    int cx = (int)floorf(vx * (1.0f / CELLW));
    int cy = (int)floorf(vy * (1.0f / CELLW));
    cx = cx < 0 ? 0 : (cx > NCX - 1 ? NCX - 1 : cx);
    cy = cy < 0 ? 0 : (cy > NCX - 1 ? NCX - 1 : cy);
    const int cell = cy * NCX + cx;
    const int k = cellCnt[cell];
    const u64 bit = 1ULL << (tid & 63);
    const int word = tid >> 6;
    if (k <= CAP) {
      for (int j = 0; j < k; ++j) {
        const int m = cellList[cell * CAP + j];
        float d = dist2d(sbx[m], sby[m], mx, my);
        if (d <= sbr[m]) atomicOr(&bm[m][word], bit);  // metric space, <=
      }
    } else {  // fallback: test all boxes (dormant)
      for (int m = 0; m < M; ++m) {
        float d = dist2d(sbx[m], sby[m], mx, my);
        if (d <= sbr[m]) atomicOr(&bm[m][word], bit);
      }
    }
  }
  __syncthreads();

  // dump bitmap (thread = box)
  if (tid < M) {
    u64* dst = bmG + ((size_t)blk * M + tid) * 4;
    dst[0] = bm[tid][0]; dst[1] = bm[tid][1];
    dst[2] = bm[tid][2]; dst[3] = bm[tid][3];
  }
}

// ---- fused per-box scan + bitmap fill + wide zero-fill. block = box, 1024 thr ----
__global__ void __launch_bounds__(1024) k_scanfill(
    const float* __restrict__ pts, const float* __restrict__ boxes,
    const u64* __restrict__ bmG, const int* __restrict__ cpng,
    const u64* __restrict__ vbits, int* __restrict__ kcount,
    int* __restrict__ sidx, u8* __restrict__ present,
    int N, int M, int S, int nchunk) {
  const int m = blockIdx.x;
  const int t = threadIdx.x;
  const int lane = t & 63, wv = t >> 6;  // 16 waves
  __shared__ int wsum[16];
  __shared__ int zws[16];

  // load my chunk's bitmap (thread t = chunk t; nchunk <= 1024)
  u64 w0 = 0, w1 = 0, w2 = 0, w3 = 0;
  int v = 0;
  if (t < nchunk) {
    const u64* bp = bmG + ((size_t)t * M + m) * 4;
    w0 = bp[0]; w1 = bp[1]; w2 = bp[2]; w3 = bp[3];
    v = __popcll(w0) + __popcll(w1) + __popcll(w2) + __popcll(w3);
  }
  // inclusive wave-shfl scan
  int incl = v;
  for (int d = 1; d < 64; d <<= 1) {
    int x = __shfl_up(incl, d);
    if (lane >= d) incl += x;
  }
  if (lane == 63) wsum[wv] = incl;
  __syncthreads();
  if (t < 16) {  // scan the 16 wave sums (lanes 0-15 of wave 0)
    int s = wsum[t];
    for (int d = 1; d < 16; d <<= 1) {
      int x = __shfl_up(s, d);
      if (t >= d) s += x;
    }
    wsum[t] = s;  // inclusive
  }
  __syncthreads();
  const int wbase = (wv > 0) ? wsum[wv - 1] : 0;
  const int off = wbase + incl - v;  // exclusive prefix over chunks
  const int total = wsum[15];
  const int k0 = total < S ? total : S;
  if (t == 0) kcount[m] = k0;

  // fill from bitmap (ascending slot = ascending point index)
  if (t < nchunk && v > 0 && off < S) {
    const int* pbase = cpng + t * 256;
    int cum = off;
    u64 ws4[4] = {w0, w1, w2, w3};
    for (int wi = 0; wi < 4 && cum < S; ++wi) {
      u64 w = ws4[wi];
      while (w && cum < S) {
        int j = (wi << 6) + __builtin_ctzll(w);
        w &= w - 1;
        int pn = pbase[j];
        sidx[m * S + cum] = pn;
        present[pn] = 1;
        ++cum;
      }
    }
  }

  // zero-fill: lowest-index non-matches (top_k tie-break among zeros)
  if (k0 >= S) return;  // uniform per block -> barrier-safe
  const float bx = boxes[m * 7 + 0], by = boxes[m * 7 + 1];
  const float r = box_radius(boxes, m);
  const u64 ltmask = (1ULL << lane) - 1ULL;
  int fill = k0;
  for (int p0 = 0; p0 < N && fill < S; p0 += 1024) {
    const int n = p0 + t;
    const bool validn = n < N;
    bool one = false;
    if (validn) {
      u64 wbit = vbits[n >> 6];  // one word per wave (broadcast)
      if ((wbit >> (n & 63)) & 1ULL) {
        float d = dist2d(bx, by, pts[n * 5 + 0], pts[n * 5 + 1]);
        one = (d <= r);
      }
    }
    const bool z = validn && !one;
    u64 b = __ballot(z);
    if (lane == 0) zws[wv] = __popcll(b);
    __syncthreads();
    int zbase = 0, ztot = 0;
    for (int ww = 0; ww < 16; ++ww) {
      int c = zws[ww];
      if (ww < wv) zbase += c;
      ztot += c;
    }
    if (z) {
      int pos = fill + zbase + __popcll(b & ltmask);
      if (pos < S) { sidx[m * S + pos] = n; present[n] = 1; }
    }
    fill += ztot;
    __syncthreads();
  }
}

// ------------------------- presence scan (rank = inverse) ----------------------
__global__ void k_bsum(const u8* __restrict__ present, int* __restrict__ bsum, int N) {
  const int n = blockIdx.x * 256 + threadIdx.x;
  bool f = (n < N) && present[n];
  u64 b = __ballot(f);
  __shared__ int ws[4];
  if ((threadIdx.x & 63) == 0) ws[threadIdx.x >> 6] = __popcll(b);
  __syncthreads();
  if (threadIdx.x == 0) bsum[blockIdx.x] = ws[0] + ws[1] + ws[2] + ws[3];
}

__global__ void __launch_bounds__(1024) k_scan(const int* __restrict__ bsum,
                                               int* __restrict__ boff, int nb) {
  __shared__ int s[1024];
  const int t = threadIdx.x;
  int v = (t < nb) ? bsum[t] : 0;
  s[t] = v;
  __syncthreads();
  for (int d = 1; d < 1024; d <<= 1) {
    int x = (t >= d) ? s[t - d] : 0;
    __syncthreads();
    s[t] += x;
    __syncthreads();
  }
  boff[t] = s[t] - v;                 // exclusive
  if (t == nb - 1) boff[1024] = s[t]; // U = total unique count
}

__global__ void k_rank(const u8* __restrict__ present, const int* __restrict__ boff,
                       const float* __restrict__ pts, int* __restrict__ rank_arr,
                       float* __restrict__ out_query, int N) {
  const int t = threadIdx.x;
  const int n = blockIdx.x * 256 + t;
  bool f = (n < N) && present[n];
  u64 b = __ballot(f);
  __shared__ int ws[4];
  const int wv = t >> 6, lane = t & 63;
  if (lane == 0) ws[wv] = __popcll(b);
  __syncthreads();
  int base = boff[blockIdx.x];
  for (int w = 0; w < wv; ++w) base += ws[w];
  if (f) {
    int rank = base + __popcll(b & ((1ULL << lane) - 1ULL));
    rank_arr[n] = rank;
    float* q = out_query + (size_t)rank * 5;
    const float* p = pts + (size_t)n * 5;
    q[0] = p[0]; q[1] = p[1]; q[2] = p[2]; q[3] = p[3]; q[4] = p[4];
  }
}

// --------- merged: outputs 0 (sampled) + 1 (idx) + query padding rows >= U ------
__global__ void k_outpad(const float* __restrict__ pts, const int* __restrict__ sidx,
                         const int* __restrict__ kcount, const int* __restrict__ rank_arr,
                         const int* __restrict__ uptr,
                         float* __restrict__ out_samp, float* __restrict__ out_idx,
                         float* __restrict__ out_query, int MS, int S) {
  const int e = blockIdx.x * 256 + threadIdx.x;
  if (e >= MS) return;
  const int U = *uptr;
  if (e >= U) {  // pad query rows with points[0] (unique fill_value=0)
    float* q = out_query + (size_t)e * 5;
    q[0] = pts[0]; q[1] = pts[1]; q[2] = pts[2]; q[3] = pts[3]; q[4] = pts[4];
  }
  const int m = e / S;
  const int s = e - m * S;
  float* o = out_samp + (size_t)e * 5;
  if (s < kcount[m]) {
    int n = sidx[e];
    const float* p = pts + (size_t)n * 5;
    o[0] = p[0]; o[1] = p[1]; o[2] = p[2]; o[3] = p[3]; o[4] = p[4];
    out_idx[e] = (float)rank_arr[n];   // idx section read back as f32; exact
  } else {
    o[0] = 0.f; o[1] = 0.f; o[2] = 0.f; o[3] = 0.f; o[4] = 0.f;
    out_idx[e] = 0.f;
  }
}

extern "C" void kernel_launch(void* const* d_in, const int* in_sizes, int n_in,
                              void* d_out, int out_size, void* d_ws, size_t ws_size,
                              hipStream_t stream) {
  const float* pts = (const float*)d_in[0];
  const float* boxes = (const float*)d_in[1];
  const float* pc_start = (const float*)d_in[2];
  const int N = in_sizes[0] / 5;
  const int M = in_sizes[1] / 7;
  const int S = out_size / (M * 11);   // out = M*S*5 + M*S + M*S*5
  const int MS = M * S;

  float* out_samp = (float*)d_out;
  float* out_idx = out_samp + (size_t)MS * 5;
  float* out_query = out_idx + (size_t)MS;

  const int nb = (N + 255) / 256;   // = nchunk; 782 for N=200000 (<=1024 for scans)
  const int nchunk = nb;

  // workspace layout (16B-aligned slices)
  char* w = (char*)d_ws;
  auto take = [&](size_t bytes) {
    char* p = w;
    w += (bytes + 15) & ~(size_t)15;
    return (void*)p;
  };
  u64* vbits     = (u64*)take((size_t)(nb * 4) * 8);
  u64* bmG       = (u64*)take((size_t)nchunk * M * 4 * 8);
  int* cpng      = (int*)take((size_t)nchunk * 256 * 4);
  int* sidx      = (int*)take((size_t)MS * 4);
  int* kcount    = (int*)take((size_t)M * 4);
  int* rank_arr  = (int*)take((size_t)N * 4);
  int* bsum      = (int*)take((size_t)1024 * 4);
  int* boff      = (int*)take((size_t)1025 * 4);
  u8*  present   = (u8*)take((size_t)N);
  float* qxv     = (float*)take((size_t)M * 4);
  float* qyv     = (float*)take((size_t)M * 4);
  float* rv      = (float*)take((size_t)M * 4);
  int* cellCnt   = (int*)take((size_t)NCX * NCX * 4);
  u16* cellList  = (u16*)take((size_t)NCX * NCX * CAP * 2);

  k_prep<<<NCX * NCX + 1, 256, 0, stream>>>(boxes, pc_start, qxv, qyv, rv,
                                            cellCnt, cellList, M);
  k_vmask_count<<<nb, 256, 0, stream>>>(pts, boxes, qxv, qyv, rv, cellCnt, cellList,
                                        vbits, present, bmG, cpng, pc_start, N, M);
  k_scanfill<<<M, 1024, 0, stream>>>(pts, boxes, bmG, cpng, vbits, kcount,
                                     sidx, present, N, M, S, nchunk);
  k_bsum<<<nb, 256, 0, stream>>>(present, bsum, N);
  k_scan<<<1, 1024, 0, stream>>>(bsum, boff, nb);
  k_rank<<<nb, 256, 0, stream>>>(present, boff, pts, rank_arr, out_query, N);
  k_outpad<<<(MS + 255) / 256, 256, 0, stream>>>(pts, sidx, kcount, rank_arr, boff + 1024,
                                                 out_samp, out_idx, out_query, MS, S);
}